// Round 3
// baseline (821.417 us; speedup 1.0000x reference)
//
#include <hip/hip_runtime.h>

// LangNN: 10-step LSTM encoder + 10-step LSTM decoder + actor head.
// B=131072, H=25, A=18. fp32. One thread = one batch element.
//
// Round-3 structure: phase-split (full encoder, then full decoder) inside one
// kernel to keep live registers ~75-100 (round 1/2's fused loop needed 125+
// live -> scratch spills -> 700 MB of HBM fetch). Encoder h goes out through
// an LDS staging buffer (coalesced float4 stores); decoder re-reads it per
// step through the same buffer (L2-resident, written by the same block).

#define HH 25
#define G4 100   // 4*H gate rows
#define PAD 28   // row padding keeps每 row 16B-aligned for ds_read_b128 merges
#define NSTEP 10
#define AOUT 18
#define BLK 256

__device__ __forceinline__ float frcp(float x) { return __builtin_amdgcn_rcpf(x); }
__device__ __forceinline__ float sigm(float x) { return frcp(1.0f + __expf(-x)); }
__device__ __forceinline__ float tanh_fast(float x) {
    float e = __expf(-2.0f * fabsf(x));
    float r = (1.0f - e) * frcp(1.0f + e);
    return copysignf(r, x);
}

__global__ __launch_bounds__(BLK)
void langnn_kernel(const float* __restrict__ state,
                   const float* __restrict__ Wih_e, const float* __restrict__ Whh_e,
                   const float* __restrict__ bih_e, const float* __restrict__ bhh_e,
                   const float* __restrict__ Wih_d, const float* __restrict__ Whh_d,
                   const float* __restrict__ bih_d, const float* __restrict__ bhh_d,
                   const float* __restrict__ Wact, const float* __restrict__ bact,
                   float* __restrict__ out, int B)
{
    __shared__ float sWcE [G4][PAD];   // encoder W_ih + W_hh (steps 1..9)
    __shared__ float sWihD[G4][PAD];
    __shared__ float sWhhD[G4][PAD];
    __shared__ float sWA  [AOUT][PAD];
    __shared__ float sbE[G4], sbD[G4], sbA[AOUT];
    __shared__ __align__(16) float sStage[BLK * HH];   // 25.6 KB staging

    const int tid = threadIdx.x;
    for (int i = tid; i < G4 * HH; i += BLK) {
        int r = i / HH, c = i % HH;
        sWcE [r][c] = Wih_e[i] + Whh_e[i];
        sWihD[r][c] = Wih_d[i];
        sWhhD[r][c] = Whh_d[i];
    }
    for (int i = tid; i < AOUT * HH; i += BLK) sWA[i / HH][i % HH] = Wact[i];
    for (int i = tid; i < G4; i += BLK) {
        sbE[i] = bih_e[i] + bhh_e[i];
        sbD[i] = bih_d[i] + bhh_d[i];
    }
    if (tid < AOUT) sbA[tid] = bact[tid];
    __syncthreads();

    const int b = blockIdx.x * BLK + tid;            // B % 256 == 0
    float* encBase = out + (size_t)B * AOUT;
    const size_t blkOff = (size_t)blockIdx.x * (BLK * HH);

    // =========================== encoder phase ===========================
    float he[HH], ce[HH], hn[HH];
    #pragma unroll
    for (int k = 0; k < HH; ++k) he[k] = state[(size_t)b * HH + k];

    // staged coalesced store of current he as enc step t
    auto storeStep = [&](int t) {
        #pragma unroll
        for (int k = 0; k < HH; ++k) sStage[tid * HH + k] = he[k];
        __syncthreads();
        const float4* s4 = (const float4*)sStage;
        float4* d4 = (float4*)(encBase + (size_t)t * B * HH + blkOff);
        #pragma unroll 1
        for (int i = tid; i < (BLK * HH) / 4; i += BLK) d4[i] = s4[i];
        __syncthreads();
    };

    // t = 0 (h=c=0): only i,g,o gates; W_ih_e uniform -> scalar loads from global
    #pragma unroll
    for (int j = 0; j < HH; ++j) {
        float ai = sbE[j], ag = sbE[2 * HH + j], ao = sbE[3 * HH + j];
        #pragma unroll
        for (int k = 0; k < HH; ++k) {
            float xv = he[k];
            ai = fmaf(Wih_e[j * HH + k],            xv, ai);
            ag = fmaf(Wih_e[(2 * HH + j) * HH + k], xv, ag);
            ao = fmaf(Wih_e[(3 * HH + j) * HH + k], xv, ao);
        }
        float cn = sigm(ai) * tanh_fast(ag);
        ce[j] = cn;
        hn[j] = sigm(ao) * tanh_fast(cn);
    }
    #pragma unroll
    for (int k = 0; k < HH; ++k) he[k] = hn[k];
    storeStep(0);

    #pragma unroll 1
    for (int t = 1; t < NSTEP; ++t) {
        // input == recurrent h -> combined weights
        #pragma unroll
        for (int j = 0; j < HH; ++j) {
            float ai = sbE[j], af = sbE[HH + j], ag = sbE[2 * HH + j], ao = sbE[3 * HH + j];
            #pragma unroll
            for (int k = 0; k < HH; ++k) {
                float xv = he[k];
                ai = fmaf(sWcE[j][k],          xv, ai);
                af = fmaf(sWcE[HH + j][k],     xv, af);
                ag = fmaf(sWcE[2 * HH + j][k], xv, ag);
                ao = fmaf(sWcE[3 * HH + j][k], xv, ao);
            }
            float cn = sigm(af) * ce[j] + sigm(ai) * tanh_fast(ag);
            ce[j] = cn;
            hn[j] = sigm(ao) * tanh_fast(cn);
        }
        #pragma unroll
        for (int k = 0; k < HH; ++k) he[k] = hn[k];
        storeStep(t);
    }

    // =========================== decoder phase ===========================
    float hd[HH], cd[HH];

    // staged coalesced load of enc step t into sStage (written by this block)
    auto loadStep = [&](int t) {
        __syncthreads();   // previous step's sStage readers done
        const float4* s4 = (const float4*)(encBase + (size_t)t * B * HH + blkOff);
        float4* d4 = (float4*)sStage;
        #pragma unroll 1
        for (int i = tid; i < (BLK * HH) / 4; i += BLK) d4[i] = s4[i];
        __syncthreads();
    };

    // t = 0 (h=c=0): only i,g,o gates; x read from LDS
    loadStep(0);
    #pragma unroll
    for (int j = 0; j < HH; ++j) {
        float ai = sbD[j], ag = sbD[2 * HH + j], ao = sbD[3 * HH + j];
        #pragma unroll
        for (int k = 0; k < HH; ++k) {
            float xv = sStage[tid * HH + k];
            ai = fmaf(sWihD[j][k],          xv, ai);
            ag = fmaf(sWihD[2 * HH + j][k], xv, ag);
            ao = fmaf(sWihD[3 * HH + j][k], xv, ao);
        }
        float cn = sigm(ai) * tanh_fast(ag);
        cd[j] = cn;
        hd[j] = sigm(ao) * tanh_fast(cn);
    }

    #pragma unroll 1
    for (int t = 1; t < NSTEP; ++t) {
        loadStep(t);
        #pragma unroll
        for (int j = 0; j < HH; ++j) {
            float ai = sbD[j], af = sbD[HH + j], ag = sbD[2 * HH + j], ao = sbD[3 * HH + j];
            #pragma unroll
            for (int k = 0; k < HH; ++k) {
                float xv = sStage[tid * HH + k];
                float hv = hd[k];
                ai = fmaf(sWihD[j][k],          xv, ai);
                ai = fmaf(sWhhD[j][k],          hv, ai);
                af = fmaf(sWihD[HH + j][k],     xv, af);
                af = fmaf(sWhhD[HH + j][k],     hv, af);
                ag = fmaf(sWihD[2 * HH + j][k], xv, ag);
                ag = fmaf(sWhhD[2 * HH + j][k], hv, ag);
                ao = fmaf(sWihD[3 * HH + j][k], xv, ao);
                ao = fmaf(sWhhD[3 * HH + j][k], hv, ao);
            }
            float cn = sigm(af) * cd[j] + sigm(ai) * tanh_fast(ag);
            cd[j] = cn;
            hn[j] = sigm(ao) * tanh_fast(cn);
        }
        #pragma unroll
        for (int k = 0; k < HH; ++k) hd[k] = hn[k];
    }

    // =========================== actor head ===========================
    __syncthreads();   // done reading sStage (step 9)
    #pragma unroll
    for (int a = 0; a < AOUT; ++a) {
        float acc = sbA[a];
        #pragma unroll
        for (int k = 0; k < HH; ++k) acc = fmaf(sWA[a][k], hd[k], acc);
        sStage[tid * AOUT + a] = acc;
    }
    __syncthreads();
    {
        const float4* s4 = (const float4*)sStage;
        float4* d4 = (float4*)(out + (size_t)blockIdx.x * (BLK * AOUT));
        #pragma unroll 1
        for (int i = tid; i < (BLK * AOUT) / 4; i += BLK) d4[i] = s4[i];
    }
}

extern "C" void kernel_launch(void* const* d_in, const int* in_sizes, int n_in,
                              void* d_out, int out_size, void* d_ws, size_t ws_size,
                              hipStream_t stream) {
    const float* state = (const float*)d_in[0];
    const float* Wih_e = (const float*)d_in[1];
    const float* Whh_e = (const float*)d_in[2];
    const float* bih_e = (const float*)d_in[3];
    const float* bhh_e = (const float*)d_in[4];
    const float* Wih_d = (const float*)d_in[5];
    const float* Whh_d = (const float*)d_in[6];
    const float* bih_d = (const float*)d_in[7];
    const float* bhh_d = (const float*)d_in[8];
    const float* Wact  = (const float*)d_in[9];
    const float* bact  = (const float*)d_in[10];

    int B = in_sizes[0] / HH;
    int grid = (B + BLK - 1) / BLK;

    hipLaunchKernelGGL(langnn_kernel, dim3(grid), dim3(BLK), 0, stream,
                       state, Wih_e, Whh_e, bih_e, bhh_e,
                       Wih_d, Whh_d, bih_d, bhh_d, Wact, bact,
                       (float*)d_out, B);
}

// Round 4
// 318.833 us; speedup vs baseline: 2.5763x; 2.5763x over previous
//
#include <hip/hip_runtime.h>

// LangNN via MFMA: 10-step LSTM encoder + decoder + actor head.
// B=131072, H=25, A=18. One wave = 32 batch rows (M=32).
// Gates packed as N=128: 4 tiles of 32 cols, tile == gate (i,f,g,o).
// mfma_f32_32x32x16_bf16: C/D layout col=lane&31, row=(reg&3)+8*(reg>>2)+4*(lane>>5)
// => lane holds all 4 gates for its (rows, j=lane&31) at the same reg index.
// Weights pre-scaled by -log2e (i,f,o) / +2log2e (g) so activations are
// exp2-based: sigm=rcp(1+exp2(y)), tanh=1-2*rcp(1+exp2(z)).
// h recurrence goes through per-wave LDS bf16 buffers (no cross-wave sync).

#define HH 25
#define NSTEP 10
#define AOUT 18
#define WAVES 4
#define ROWS 32
#define NFRAG 34
#define LOG2E 1.44269504088896340736f

typedef __attribute__((ext_vector_type(8))) short short8;
typedef __attribute__((ext_vector_type(16))) float f32x16;

__device__ __forceinline__ short f2bf(float x) {   // f32 -> bf16 bits (RNE)
    unsigned u = __float_as_uint(x);
    u += 0x7fffu + ((u >> 16) & 1u);
    return (short)(u >> 16);
}

#define MFMA(a, b, c) __builtin_amdgcn_mfma_f32_32x32x16_bf16((a), (b), (c), 0, 0, 0)

__global__ __launch_bounds__(256)
void langnn_mfma(const float* __restrict__ state,
                 const float* __restrict__ Wih_e, const float* __restrict__ Whh_e,
                 const float* __restrict__ bih_e, const float* __restrict__ bhh_e,
                 const float* __restrict__ Wih_d, const float* __restrict__ Whh_d,
                 const float* __restrict__ bih_d, const float* __restrict__ bhh_d,
                 const float* __restrict__ Wact, const float* __restrict__ bact,
                 float* __restrict__ out, int B)
{
    // frag table: idx 0..7 encW(step0) | 8..15 enc(Wih+Whh) | 16..23 decX |
    //             24..31 decH | 32..33 actor.  idx within set = nt*2+kf.
    __shared__ __align__(16) short sFrag[NFRAG][64][8];      // 34 KB
    __shared__ __align__(16) short sHE[WAVES][ROWS][32];     // 8 KB
    __shared__ __align__(16) short sHD[WAVES][ROWS][32];     // 8 KB

    const int tid  = threadIdx.x;
    const int lane = tid & 63;
    const int wave = tid >> 6;
    const int j    = lane & 31;   // A-row / B-col / C-col
    const int gsel = lane >> 5;
    const int kb   = gsel * 8;    // k base within a K=16 fragment

    // ---- build B-fragment table (one wave's worth of lanes suffices) ----
    if (tid < 64) {
        const float scl[4] = {-LOG2E, -LOG2E, 2.f * LOG2E, -LOG2E};
        for (int idx = 0; idx < NFRAG; ++idx) {
            const float *W1, *W2 = nullptr; float sc; int nt, kf, jmax = HH;
            if (idx < 8)       { nt = idx >> 1;        kf = idx & 1; W1 = Wih_e; sc = scl[nt]; }
            else if (idx < 16) { nt = (idx - 8) >> 1;  kf = idx & 1; W1 = Wih_e; W2 = Whh_e; sc = scl[nt]; }
            else if (idx < 24) { nt = (idx - 16) >> 1; kf = idx & 1; W1 = Wih_d; sc = scl[nt]; }
            else if (idx < 32) { nt = (idx - 24) >> 1; kf = idx & 1; W1 = Whh_d; sc = scl[nt]; }
            else               { nt = 0;               kf = idx - 32; W1 = Wact; sc = 1.f; jmax = AOUT; }
            const int n = nt * HH + j;         // weight row (gate*25+j); actor: j
            for (int e = 0; e < 8; ++e) {
                const int k = kf * 16 + kb + e;
                float v = 0.f;
                if (j < jmax && k < HH) {
                    v = W1[n * HH + k];
                    if (W2) v += W2[n * HH + k];
                    v *= sc;
                }
                sFrag[idx][lane][e] = f2bf(v);
            }
        }
    }
    // biases into regs (scaled like the weights)
    float bE[4], bD[4];
    {
        const float scl[4] = {-LOG2E, -LOG2E, 2.f * LOG2E, -LOG2E};
        #pragma unroll
        for (int gt = 0; gt < 4; ++gt) {
            bE[gt] = (j < HH) ? scl[gt] * (bih_e[gt * HH + j] + bhh_e[gt * HH + j]) : 0.f;
            bD[gt] = (j < HH) ? scl[gt] * (bih_d[gt * HH + j] + bhh_d[gt * HH + j]) : 0.f;
        }
    }
    const float bA = (j < AOUT) ? bact[j] : 0.f;

    __syncthreads();

    // zero this wave's h buffers (cols 25..31 must stay 0; hd starts at 0)
    {
        int* zE = (int*)&sHE[wave][0][0];
        int* zD = (int*)&sHD[wave][0][0];
        #pragma unroll
        for (int i = 0; i < (ROWS * 32 / 2) / 64; ++i) { zE[lane + i * 64] = 0; zD[lane + i * 64] = 0; }
    }

    const int b0 = (blockIdx.x * WAVES + wave) * ROWS;
    float* encOut = out + (size_t)B * AOUT;
    float ce[16], cd[16];
    #pragma unroll
    for (int q = 0; q < 16; ++q) { ce[q] = 0.f; cd[q] = 0.f; }

    // initial encoder A-fragments from state (bf16)
    short8 aE0, aE1;
    {
        const float* sp = state + (size_t)(b0 + j) * HH;
        #pragma unroll
        for (int e = 0; e < 8; ++e) {
            const int k1 = 16 + kb + e;
            aE0[e] = f2bf(sp[kb + e]);                    // k <= 15 < 25
            aE1[e] = f2bf(k1 < HH ? sp[k1] : 0.f);
        }
    }

    #pragma unroll 1
    for (int t = 0; t < NSTEP; ++t) {
        // ---------------- encoder ----------------
        const int base = (t == 0) ? 0 : 8;   // step0: W_ih only; else combined
        f32x16 acc[4];
        #pragma unroll
        for (int gt = 0; gt < 4; ++gt) {
            f32x16 a;
            #pragma unroll
            for (int q = 0; q < 16; ++q) a[q] = bE[gt];
            short8 bf0 = *(const short8*)&sFrag[base + gt * 2 + 0][lane][0];
            short8 bf1 = *(const short8*)&sFrag[base + gt * 2 + 1][lane][0];
            a = MFMA(aE0, bf0, a);
            a = MFMA(aE1, bf1, a);
            acc[gt] = a;
        }
        float hv[16];
        #pragma unroll
        for (int q = 0; q < 16; ++q) {
            float Ei = exp2f(acc[0][q]);
            float Ef = exp2f(acc[1][q]);
            float Eg = exp2f(acc[2][q]);
            float Eo = exp2f(acc[3][q]);
            float sf = __builtin_amdgcn_rcpf(1.f + Ef);
            float st = (Eg - 1.f) * __builtin_amdgcn_rcpf((1.f + Ei) * (1.f + Eg)); // sig(i)*tanh(g)
            float c  = fmaf(sf, ce[q], st);
            ce[q] = c;
            float Ec = exp2f(c * (2.f * LOG2E));
            hv[q] = (Ec - 1.f) * __builtin_amdgcn_rcpf((1.f + Ec) * (1.f + Eo));    // sig(o)*tanh(c)
        }
        {   // store enc h (f32, pre-rounding) + bf16 into hbufE
            float* ep = encOut + (size_t)t * B * HH + (size_t)b0 * HH;
            if (j < HH) {
                #pragma unroll
                for (int q = 0; q < 16; ++q) {
                    const int row = (q & 3) + 8 * (q >> 2) + 4 * gsel;
                    ep[row * HH + j] = hv[q];
                    sHE[wave][row][j] = f2bf(hv[q]);
                }
            }
        }
        // rebuild encoder A (input == recurrent h)
        aE0 = *(const short8*)&sHE[wave][j][kb];
        aE1 = *(const short8*)&sHE[wave][j][16 + kb];

        // ---------------- decoder ----------------
        short8 aD0 = *(const short8*)&sHD[wave][j][kb];        // previous hd (0 at t=0)
        short8 aD1 = *(const short8*)&sHD[wave][j][16 + kb];
        #pragma unroll
        for (int gt = 0; gt < 4; ++gt) {
            f32x16 a;
            #pragma unroll
            for (int q = 0; q < 16; ++q) a[q] = bD[gt];
            short8 bx0 = *(const short8*)&sFrag[16 + gt * 2 + 0][lane][0];
            short8 bx1 = *(const short8*)&sFrag[16 + gt * 2 + 1][lane][0];
            short8 bh0 = *(const short8*)&sFrag[24 + gt * 2 + 0][lane][0];
            short8 bh1 = *(const short8*)&sFrag[24 + gt * 2 + 1][lane][0];
            a = MFMA(aE0, bx0, a);
            a = MFMA(aE1, bx1, a);
            a = MFMA(aD0, bh0, a);
            a = MFMA(aD1, bh1, a);
            acc[gt] = a;
        }
        #pragma unroll
        for (int q = 0; q < 16; ++q) {
            float Ei = exp2f(acc[0][q]);
            float Ef = exp2f(acc[1][q]);
            float Eg = exp2f(acc[2][q]);
            float Eo = exp2f(acc[3][q]);
            float sf = __builtin_amdgcn_rcpf(1.f + Ef);
            float st = (Eg - 1.f) * __builtin_amdgcn_rcpf((1.f + Ei) * (1.f + Eg));
            float c  = fmaf(sf, cd[q], st);
            cd[q] = c;
            float Ec = exp2f(c * (2.f * LOG2E));
            hv[q] = (Ec - 1.f) * __builtin_amdgcn_rcpf((1.f + Ec) * (1.f + Eo));
        }
        if (j < HH) {
            #pragma unroll
            for (int q = 0; q < 16; ++q) {
                const int row = (q & 3) + 8 * (q >> 2) + 4 * gsel;
                sHD[wave][row][j] = f2bf(hv[q]);
            }
        }
    }

    // ---------------- actor head ----------------
    {
        short8 aL0 = *(const short8*)&sHD[wave][j][kb];
        short8 aL1 = *(const short8*)&sHD[wave][j][16 + kb];
        short8 wa0 = *(const short8*)&sFrag[32][lane][0];
        short8 wa1 = *(const short8*)&sFrag[33][lane][0];
        f32x16 a;
        #pragma unroll
        for (int q = 0; q < 16; ++q) a[q] = bA;
        a = MFMA(aL0, wa0, a);
        a = MFMA(aL1, wa1, a);
        if (j < AOUT) {
            #pragma unroll
            for (int q = 0; q < 16; ++q) {
                const int row = (q & 3) + 8 * (q >> 2) + 4 * gsel;
                out[(size_t)(b0 + row) * AOUT + j] = a[q];
            }
        }
    }
}

extern "C" void kernel_launch(void* const* d_in, const int* in_sizes, int n_in,
                              void* d_out, int out_size, void* d_ws, size_t ws_size,
                              hipStream_t stream) {
    const float* state = (const float*)d_in[0];
    const float* Wih_e = (const float*)d_in[1];
    const float* Whh_e = (const float*)d_in[2];
    const float* bih_e = (const float*)d_in[3];
    const float* bhh_e = (const float*)d_in[4];
    const float* Wih_d = (const float*)d_in[5];
    const float* Whh_d = (const float*)d_in[6];
    const float* bih_d = (const float*)d_in[7];
    const float* bhh_d = (const float*)d_in[8];
    const float* Wact  = (const float*)d_in[9];
    const float* bact  = (const float*)d_in[10];

    int B = in_sizes[0] / HH;
    int grid = B / (WAVES * ROWS);   // 131072/128 = 1024

    hipLaunchKernelGGL(langnn_mfma, dim3(grid), dim3(256), 0, stream,
                       state, Wih_e, Whh_e, bih_e, bhh_e,
                       Wih_d, Whh_d, bih_d, bhh_d, Wact, bact,
                       (float*)d_out, B);
}

// Round 5
// 245.814 us; speedup vs baseline: 3.3416x; 1.2970x over previous
//
#include <hip/hip_runtime.h>

// LangNN via 16x16x32 MFMA: 10-step LSTM encoder + decoder + actor head.
// B=131072, H=25, A=18. One wave = 32 batch rows as TWO 16-row M-tiles
// (each B-frag LDS read feeds 2 MFMAs). Gates processed in two sequential
// 16-col jt-phases to keep acc = 32 regs (round 4's f32x16 acc pushed
// VGPR+AGPR past 256 -> 1 wave/SIMD -> latency-bound at 339us).
// C/D layout (m89-verified): col=lane&15, row=(lane>>4)*4+q.
// A/B built with the same (lane,e)->k convention so k-permutations cancel.
// Weights pre-scaled by -log2e (i,f,o) / +2log2e (g): exp2-based activations.

#define HH 25
#define NSTEP 10
#define AOUT 18
#define WPB 4
#define BLK (WPB * 64)
#define MT 2
#define ROWS (MT * 16)        // 32 rows per wave
#define NFRG 26
#define FPAD 40               // h-staging feature stride (80 B: 2-way-conflict reads)
#define LOG2E 1.44269504088896340736f

typedef __attribute__((ext_vector_type(8))) short short8;
typedef __attribute__((ext_vector_type(4))) float f32x4;

__device__ __forceinline__ short f2bf(float x) {   // f32 -> bf16 bits (RNE)
    unsigned u = __float_as_uint(x);
    u += 0x7fffu + ((u >> 16) & 1u);
    return (short)(u >> 16);
}

#define MFMA16(a, b, c) __builtin_amdgcn_mfma_f32_16x16x32_bf16((a), (b), (c), 0, 0, 0)

__global__ __launch_bounds__(BLK)
void langnn_mfma16(const float* __restrict__ state,
                   const float* __restrict__ Wih_e, const float* __restrict__ Whh_e,
                   const float* __restrict__ bih_e, const float* __restrict__ bhh_e,
                   const float* __restrict__ Wih_d, const float* __restrict__ Whh_d,
                   const float* __restrict__ bih_d, const float* __restrict__ bhh_d,
                   const float* __restrict__ Wact, const float* __restrict__ bact,
                   float* __restrict__ out, int B)
{
    // frag sets: 0..7 enc combined (Wih+Whh) [gt*2+jt] | 8..15 decX | 16..23 decH
    //            | 24..25 actor [jt]
    __shared__ __align__(16) short sFrag[NFRG][64][8];          // 26 KB
    __shared__ __align__(16) short sH[WPB][2][MT][16][FPAD];    // 20.5 KB (cell 0=he,1=hd)

    const int tid  = threadIdx.x;
    const int lane = tid & 63;
    const int w    = tid >> 6;
    const int r    = lane & 15;    // A-row / B,C-col lane index
    const int g    = lane >> 4;    // k-group / C row-group

    const float scl[4] = {-LOG2E, -LOG2E, 2.f * LOG2E, -LOG2E};

    // ---- build B-fragment table ----
    for (int i = tid; i < NFRG * 64; i += BLK) {
        const int idx = i >> 6, l = i & 63;
        const int lj = l & 15, lg = l >> 4;
        const float *W1, *W2 = nullptr; float sc = 1.f; int gt = 0, jt, jmax = HH;
        if (idx < 8)       { gt = idx >> 1;        jt = idx & 1; W1 = Wih_e; W2 = Whh_e; sc = scl[gt]; }
        else if (idx < 16) { gt = (idx - 8) >> 1;  jt = idx & 1; W1 = Wih_d; sc = scl[gt]; }
        else if (idx < 24) { gt = (idx - 16) >> 1; jt = idx & 1; W1 = Whh_d; sc = scl[gt]; }
        else               { jt = idx - 24;        W1 = Wact;    jmax = AOUT; }
        const int col = jt * 16 + lj;
        const int n = gt * HH + col;
        for (int e = 0; e < 8; ++e) {
            const int k = lg * 8 + e;
            float v = 0.f;
            if (col < jmax && k < HH) {
                v = W1[n * HH + k];
                if (W2) v += W2[n * HH + k];
                v *= sc;
            }
            sFrag[idx][l][e] = f2bf(v);
        }
    }
    // ---- zero h staging (cols 25..31 must read as 0; hd starts at 0) ----
    {
        int* z = (int*)&sH[0][0][0][0][0];
        const int n32 = (int)(sizeof(sH) / 4);
        for (int i = tid; i < n32; i += BLK) z[i] = 0;
    }

    // ---- biases (scaled like the weights) ----
    float bE[2][4], bD[2][4], bA[2];
    #pragma unroll
    for (int jt = 0; jt < 2; ++jt) {
        const int col = jt * 16 + r;
        #pragma unroll
        for (int gt = 0; gt < 4; ++gt) {
            bE[jt][gt] = (col < HH) ? scl[gt] * (bih_e[gt * HH + col] + bhh_e[gt * HH + col]) : 0.f;
            bD[jt][gt] = (col < HH) ? scl[gt] * (bih_d[gt * HH + col] + bhh_d[gt * HH + col]) : 0.f;
        }
        bA[jt] = (col < AOUT) ? bact[col] : 0.f;
    }
    __syncthreads();

    const int b0 = (blockIdx.x * WPB + w) * ROWS;
    float* encOut = out + (size_t)B * AOUT;

    float ce[MT][2][4], cd[MT][2][4];
    #pragma unroll
    for (int m = 0; m < MT; ++m)
        #pragma unroll
        for (int jt = 0; jt < 2; ++jt)
            #pragma unroll
            for (int q = 0; q < 4; ++q) { ce[m][jt][q] = 0.f; cd[m][jt][q] = 0.f; }

    // initial encoder A-fragments from state: lane holds row r, k = g*8+e
    short8 aE[MT];
    #pragma unroll
    for (int m = 0; m < MT; ++m) {
        const float* sp = state + (size_t)(b0 + m * 16 + r) * HH;
        #pragma unroll
        for (int e = 0; e < 8; ++e) {
            const int k = g * 8 + e;
            aE[m][e] = (k < HH) ? f2bf(sp[k]) : (short)0;
        }
    }

    #pragma unroll 1
    for (int t = 0; t < NSTEP; ++t) {
        float* encRow = encOut + (size_t)t * B * HH;
        // ===================== encoder =====================
        #pragma unroll
        for (int jt = 0; jt < 2; ++jt) {
            f32x4 acc[MT][4];
            #pragma unroll
            for (int gt = 0; gt < 4; ++gt) {
                short8 Bf;
                if (t == 0) {   // step 0: W_ih_e only (h=0), built from global once
                    const int col = jt * 16 + r;
                    #pragma unroll
                    for (int e = 0; e < 8; ++e) {
                        const int k = g * 8 + e;
                        float v = (col < HH && k < HH)
                                    ? scl[gt] * Wih_e[(gt * HH + col) * HH + k] : 0.f;
                        Bf[e] = f2bf(v);
                    }
                } else {
                    Bf = *(const short8*)&sFrag[gt * 2 + jt][lane][0];
                }
                f32x4 c0; c0[0] = c0[1] = c0[2] = c0[3] = bE[jt][gt];
                #pragma unroll
                for (int m = 0; m < MT; ++m) acc[m][gt] = MFMA16(aE[m], Bf, c0);
            }
            const int col = jt * 16 + r;
            #pragma unroll
            for (int m = 0; m < MT; ++m) {
                #pragma unroll
                for (int q = 0; q < 4; ++q) {
                    float Ei = exp2f(acc[m][0][q]);
                    float Ef = exp2f(acc[m][1][q]);
                    float Eg = exp2f(acc[m][2][q]);
                    float Eo = exp2f(acc[m][3][q]);
                    float st = (Eg - 1.f) * __builtin_amdgcn_rcpf((1.f + Ei) * (1.f + Eg));
                    float c  = fmaf(__builtin_amdgcn_rcpf(1.f + Ef), ce[m][jt][q], st);
                    ce[m][jt][q] = c;
                    float Ec = exp2f(2.f * LOG2E * c);
                    float h = (Ec - 1.f) * __builtin_amdgcn_rcpf((1.f + Ec) * (1.f + Eo));
                    if (col < HH) {
                        encRow[(size_t)(b0 + m * 16 + g * 4 + q) * HH + col] = h;
                        sH[w][0][m][g * 4 + q][col] = f2bf(h);
                    }
                }
            }
        }
        // reload he fragments (enc input for t+1 AND dec x for this step)
        #pragma unroll
        for (int m = 0; m < MT; ++m)
            aE[m] = *(const short8*)&sH[w][0][m][r][g * 8];

        // ===================== decoder =====================
        short8 aD[MT];   // hd(t-1); zeros at t=0 (pre-zeroed staging)
        #pragma unroll
        for (int m = 0; m < MT; ++m)
            aD[m] = *(const short8*)&sH[w][1][m][r][g * 8];
        #pragma unroll
        for (int jt = 0; jt < 2; ++jt) {
            f32x4 acc[MT][4];
            #pragma unroll
            for (int gt = 0; gt < 4; ++gt) {
                short8 Bx = *(const short8*)&sFrag[8 + gt * 2 + jt][lane][0];
                short8 Bh = *(const short8*)&sFrag[16 + gt * 2 + jt][lane][0];
                f32x4 c0; c0[0] = c0[1] = c0[2] = c0[3] = bD[jt][gt];
                #pragma unroll
                for (int m = 0; m < MT; ++m)
                    acc[m][gt] = MFMA16(aD[m], Bh, MFMA16(aE[m], Bx, c0));
            }
            const int col = jt * 16 + r;
            #pragma unroll
            for (int m = 0; m < MT; ++m) {
                #pragma unroll
                for (int q = 0; q < 4; ++q) {
                    float Ei = exp2f(acc[m][0][q]);
                    float Ef = exp2f(acc[m][1][q]);
                    float Eg = exp2f(acc[m][2][q]);
                    float Eo = exp2f(acc[m][3][q]);
                    float st = (Eg - 1.f) * __builtin_amdgcn_rcpf((1.f + Ei) * (1.f + Eg));
                    float c  = fmaf(__builtin_amdgcn_rcpf(1.f + Ef), cd[m][jt][q], st);
                    cd[m][jt][q] = c;
                    float Ec = exp2f(2.f * LOG2E * c);
                    float h = (Ec - 1.f) * __builtin_amdgcn_rcpf((1.f + Ec) * (1.f + Eo));
                    if (col < HH) sH[w][1][m][g * 4 + q][col] = f2bf(h);
                }
            }
        }
    }

    // ===================== actor head =====================
    short8 aL[MT];
    #pragma unroll
    for (int m = 0; m < MT; ++m)
        aL[m] = *(const short8*)&sH[w][1][m][r][g * 8];
    #pragma unroll
    for (int jt = 0; jt < 2; ++jt) {
        short8 Bf = *(const short8*)&sFrag[24 + jt][lane][0];
        const int col = jt * 16 + r;
        #pragma unroll
        for (int m = 0; m < MT; ++m) {
            f32x4 c0; c0[0] = c0[1] = c0[2] = c0[3] = bA[jt];
            f32x4 o = MFMA16(aL[m], Bf, c0);
            if (col < AOUT) {
                #pragma unroll
                for (int q = 0; q < 4; ++q)
                    out[(size_t)(b0 + m * 16 + g * 4 + q) * AOUT + col] = o[q];
            }
        }
    }
}

extern "C" void kernel_launch(void* const* d_in, const int* in_sizes, int n_in,
                              void* d_out, int out_size, void* d_ws, size_t ws_size,
                              hipStream_t stream) {
    const float* state = (const float*)d_in[0];
    const float* Wih_e = (const float*)d_in[1];
    const float* Whh_e = (const float*)d_in[2];
    const float* bih_e = (const float*)d_in[3];
    const float* bhh_e = (const float*)d_in[4];
    const float* Wih_d = (const float*)d_in[5];
    const float* Whh_d = (const float*)d_in[6];
    const float* bih_d = (const float*)d_in[7];
    const float* bhh_d = (const float*)d_in[8];
    const float* Wact  = (const float*)d_in[9];
    const float* bact  = (const float*)d_in[10];

    int B = in_sizes[0] / HH;
    int grid = B / (WPB * ROWS);   // 131072/128 = 1024

    hipLaunchKernelGGL(langnn_mfma16, dim3(grid), dim3(BLK), 0, stream,
                       state, Wih_e, Whh_e, bih_e, bhh_e,
                       Wih_d, Whh_d, bih_d, bhh_d, Wact, bact,
                       (float*)d_out, B);
}

// Round 6
// 97.695 us; speedup vs baseline: 8.4080x; 2.5162x over previous
//
#include <hip/hip_runtime.h>

// LangNN via 16x16x32 bf16 MFMA. B=131072, H=25, A=18.
// One wave = 32 batch rows (two 16-row M-tiles). Gates = 8 N-tiles (4 gates x 2 jt).
// Round-6: BLK=512 (8 waves amortize one frag table), LDS 75.8KB -> 2 blocks/CU,
// grid 512 -> full residency. launch_bounds(512,4) caps VGPR at 128 (4 waves/SIMD).
// Biases folded into MFMA via A's k=25 column == 1.0 and B's k=25 row == scaled bias
// (removes 18 bias VGPRs; biases are zero in this problem so bf16 is exact).
// exp2 via __builtin_amdgcn_exp2f; bf16 convert via v_cvt_pk_bf16_f32.
// C/D layout (verified r4/r5): col=lane&15, row=(lane>>4)*4+q.

#define HH 25
#define NSTEP 10
#define AOUT 18
#define WPB 8
#define BLK (WPB * 64)
#define MT 2
#define ROWS (MT * 16)
#define NFRG 34   // 0..7 enc(Wih+Whh) | 8..15 decX | 16..23 decH | 24..25 actor | 26..33 encW0
#define FPAD 40   // 80B row stride: 16B-aligned, 2-way-conflict b128 reads
#define LOG2E 1.44269504088896340736f

typedef __attribute__((ext_vector_type(8))) short short8;
typedef __attribute__((ext_vector_type(4))) float f32x4;

__device__ __forceinline__ short f2bf(float x) {   // f32 -> bf16 (RNE), init-path only
    unsigned u = __float_as_uint(x);
    u += 0x7fffu + ((u >> 16) & 1u);
    return (short)(u >> 16);
}
__device__ __forceinline__ unsigned cvtpk(float lo, float hi) {  // 2xf32 -> packed bf16 (RNE)
    unsigned r;
    asm("v_cvt_pk_bf16_f32 %0, %1, %2" : "=v"(r) : "v"(lo), "v"(hi));
    return r;
}
#if __has_builtin(__builtin_amdgcn_exp2f)
#define EXP2(x) __builtin_amdgcn_exp2f(x)
#else
#define EXP2(x) exp2f(x)
#endif
#define RCP(x) __builtin_amdgcn_rcpf(x)
#define MFMA16(a, b, c) __builtin_amdgcn_mfma_f32_16x16x32_bf16((a), (b), (c), 0, 0, 0)

__global__ __launch_bounds__(BLK, 4)
void langnn_mfma16(const float* __restrict__ state,
                   const float* __restrict__ Wih_e, const float* __restrict__ Whh_e,
                   const float* __restrict__ bih_e, const float* __restrict__ bhh_e,
                   const float* __restrict__ Wih_d, const float* __restrict__ Whh_d,
                   const float* __restrict__ bih_d, const float* __restrict__ bhh_d,
                   const float* __restrict__ Wact, const float* __restrict__ bact,
                   float* __restrict__ out, int B)
{
    __shared__ __align__(16) short sFrag[NFRG][64][8];          // 34 KB
    __shared__ __align__(16) short sH[WPB][2][MT][16][FPAD];    // 40 KB (cell 0=he,1=hd)

    const int tid  = threadIdx.x;
    const int lane = tid & 63;
    const int w    = tid >> 6;
    const int r    = lane & 15;    // A-row / C-col lane index
    const int g    = lane >> 4;    // k-group / C row-group

    // ---- build B-fragment table (bias in k=25 row) ----
    for (int i = tid; i < NFRG * 64; i += BLK) {
        const int idx = i >> 6, l = i & 63;
        const int lj = l & 15, lg = l >> 4;
        const float *W1 = nullptr, *W2 = nullptr, *B1 = nullptr, *B2 = nullptr;
        int gt = 0, jt, jmax = HH;
        if (idx < 8)       { gt = idx >> 1;        jt = idx & 1; W1 = Wih_e; W2 = Whh_e; B1 = bih_e; B2 = bhh_e; }
        else if (idx < 16) { gt = (idx - 8) >> 1;  jt = idx & 1; W1 = Wih_d; B1 = bih_d; B2 = bhh_d; }
        else if (idx < 24) { gt = (idx - 16) >> 1; jt = idx & 1; W1 = Whh_d; }
        else if (idx < 26) { jt = idx - 24;        W1 = Wact;    B1 = bact;  jmax = AOUT; }
        else               { gt = (idx - 26) >> 1; jt = idx & 1; W1 = Wih_e; B1 = bih_e; B2 = bhh_e; }
        const bool actor = (idx >= 24 && idx < 26);
        const float sc = actor ? 1.f : (gt == 2 ? 2.f * LOG2E : -LOG2E);
        const int col = jt * 16 + lj;
        const int nrow = actor ? col : gt * HH + col;
        for (int e = 0; e < 8; ++e) {
            const int k = lg * 8 + e;
            float v = 0.f;
            if (col < jmax) {
                if (k < HH) {
                    v = W1[nrow * HH + k];
                    if (W2) v += W2[nrow * HH + k];
                    v *= sc;
                } else if (k == HH && B1) {
                    v = B1[nrow];
                    if (B2) v += B2[nrow];
                    v *= sc;
                }
            }
            sFrag[idx][l][e] = f2bf(v);
        }
    }
    // ---- init h staging: zeros, except col 25 = 1.0 (bias lane) ----
    {
        int* z = (int*)sH;
        const int n32 = (int)(sizeof(sH) / 4);   // 20 dwords per row
        for (int i = tid; i < n32; i += BLK)
            z[i] = ((i % (FPAD / 2)) == 12) ? 0x3F800000 : 0;  // dword12 = shorts 24|25
    }
    __syncthreads();

    const int b0 = (blockIdx.x * WPB + w) * ROWS;
    float* encRow = out + (size_t)B * AOUT;

    float ce[MT][2][4], cd[MT][2][4];
    #pragma unroll
    for (int m = 0; m < MT; ++m)
        #pragma unroll
        for (int jt = 0; jt < 2; ++jt)
            #pragma unroll
            for (int q = 0; q < 4; ++q) { ce[m][jt][q] = 0.f; cd[m][jt][q] = 0.f; }

    // per-thread enc_hs store bases (advance by B*HH per step)
    float* pe[MT];
    #pragma unroll
    for (int m = 0; m < MT; ++m)
        pe[m] = encRow + (size_t)(b0 + m * 16 + g * 4) * HH + r;

    // initial A-fragments: encoder x = state (k=25 -> 1.0), decoder h = 0 (from sH)
    short8 aE[MT], aD[MT];
    #pragma unroll
    for (int m = 0; m < MT; ++m) {
        const float* sp = state + (size_t)(b0 + m * 16 + r) * HH;
        #pragma unroll
        for (int e = 0; e < 8; ++e) {
            const int k = g * 8 + e;
            aE[m][e] = (k < HH) ? f2bf(sp[k]) : (k == HH ? (short)0x3F80 : (short)0);
        }
        aD[m] = *(const short8*)&sH[w][1][m][r][g * 8];
    }

    auto encCell = [&](int fbase) {
        #pragma unroll
        for (int jt = 0; jt < 2; ++jt) {
            f32x4 acc[MT][4];
            #pragma unroll
            for (int gt = 0; gt < 4; ++gt) {
                short8 Bf = *(const short8*)&sFrag[fbase + gt * 2 + jt][lane][0];
                f32x4 z; z[0] = z[1] = z[2] = z[3] = 0.f;
                #pragma unroll
                for (int m = 0; m < MT; ++m) acc[m][gt] = MFMA16(aE[m], Bf, z);
            }
            #pragma unroll
            for (int m = 0; m < MT; ++m) {
                float hv[4];
                #pragma unroll
                for (int q = 0; q < 4; ++q) {
                    float Ei = EXP2(acc[m][0][q]);
                    float Ef = EXP2(acc[m][1][q]);
                    float Eg = EXP2(acc[m][2][q]);
                    float Eo = EXP2(acc[m][3][q]);
                    float st = (Eg - 1.f) * RCP((1.f + Ei) * (1.f + Eg));
                    float c  = fmaf(RCP(1.f + Ef), ce[m][jt][q], st);
                    ce[m][jt][q] = c;
                    float Ec = EXP2(2.f * LOG2E * c);
                    hv[q] = (Ec - 1.f) * RCP((1.f + Ec) * (1.f + Eo));
                }
                if (jt == 0 || r < 9) {
                    float* p = pe[m] + jt * 16;
                    p[0] = hv[0]; p[HH] = hv[1]; p[2 * HH] = hv[2]; p[3 * HH] = hv[3];
                    unsigned p01 = cvtpk(hv[0], hv[1]), p23 = cvtpk(hv[2], hv[3]);
                    short* sp = &sH[w][0][m][g * 4][jt * 16 + r];
                    sp[0]        = (short)p01;
                    sp[FPAD]     = (short)(p01 >> 16);
                    sp[2 * FPAD] = (short)p23;
                    sp[3 * FPAD] = (short)(p23 >> 16);
                }
            }
        }
        #pragma unroll
        for (int m = 0; m < MT; ++m) {
            aE[m] = *(const short8*)&sH[w][0][m][r][g * 8];
            pe[m] += (size_t)B * HH;
        }
    };

    auto decCell = [&]() {
        #pragma unroll
        for (int jt = 0; jt < 2; ++jt) {
            f32x4 acc[MT][4];
            #pragma unroll
            for (int gt = 0; gt < 4; ++gt) {
                short8 Bx = *(const short8*)&sFrag[8 + gt * 2 + jt][lane][0];
                short8 Bh = *(const short8*)&sFrag[16 + gt * 2 + jt][lane][0];
                f32x4 z; z[0] = z[1] = z[2] = z[3] = 0.f;
                #pragma unroll
                for (int m = 0; m < MT; ++m)
                    acc[m][gt] = MFMA16(aD[m], Bh, MFMA16(aE[m], Bx, z));
            }
            #pragma unroll
            for (int m = 0; m < MT; ++m) {
                float hv[4];
                #pragma unroll
                for (int q = 0; q < 4; ++q) {
                    float Ei = EXP2(acc[m][0][q]);
                    float Ef = EXP2(acc[m][1][q]);
                    float Eg = EXP2(acc[m][2][q]);
                    float Eo = EXP2(acc[m][3][q]);
                    float st = (Eg - 1.f) * RCP((1.f + Ei) * (1.f + Eg));
                    float c  = fmaf(RCP(1.f + Ef), cd[m][jt][q], st);
                    cd[m][jt][q] = c;
                    float Ec = EXP2(2.f * LOG2E * c);
                    hv[q] = (Ec - 1.f) * RCP((1.f + Ec) * (1.f + Eo));
                }
                if (jt == 0 || r < 9) {
                    unsigned p01 = cvtpk(hv[0], hv[1]), p23 = cvtpk(hv[2], hv[3]);
                    short* sp = &sH[w][1][m][g * 4][jt * 16 + r];
                    sp[0]        = (short)p01;
                    sp[FPAD]     = (short)(p01 >> 16);
                    sp[2 * FPAD] = (short)p23;
                    sp[3 * FPAD] = (short)(p23 >> 16);
                }
            }
        }
        #pragma unroll
        for (int m = 0; m < MT; ++m)
            aD[m] = *(const short8*)&sH[w][1][m][r][g * 8];
    };

    encCell(26);                        // enc step 0 (W_ih-only frags)
    #pragma unroll 1
    for (int t = 0; t < NSTEP - 1; ++t) {
        decCell();                      // dec step t consumes he(t)
        encCell(0);                     // enc step t+1 (combined frags)
    }
    decCell();                          // dec step 9

    // ---- actor head (bias via k=25, aD holds hd(9)) ----
    #pragma unroll
    for (int jt = 0; jt < 2; ++jt) {
        short8 Bf = *(const short8*)&sFrag[24 + jt][lane][0];
        #pragma unroll
        for (int m = 0; m < MT; ++m) {
            f32x4 z; z[0] = z[1] = z[2] = z[3] = 0.f;
            f32x4 o = MFMA16(aD[m], Bf, z);
            if (jt == 0 || r < 2) {
                float* p = out + (size_t)(b0 + m * 16 + g * 4) * AOUT + jt * 16 + r;
                p[0] = o[0]; p[AOUT] = o[1]; p[2 * AOUT] = o[2]; p[3 * AOUT] = o[3];
            }
        }
    }
}

extern "C" void kernel_launch(void* const* d_in, const int* in_sizes, int n_in,
                              void* d_out, int out_size, void* d_ws, size_t ws_size,
                              hipStream_t stream) {
    const float* state = (const float*)d_in[0];
    const float* Wih_e = (const float*)d_in[1];
    const float* Whh_e = (const float*)d_in[2];
    const float* bih_e = (const float*)d_in[3];
    const float* bhh_e = (const float*)d_in[4];
    const float* Wih_d = (const float*)d_in[5];
    const float* Whh_d = (const float*)d_in[6];
    const float* bih_d = (const float*)d_in[7];
    const float* bhh_d = (const float*)d_in[8];
    const float* Wact  = (const float*)d_in[9];
    const float* bact  = (const float*)d_in[10];

    int B = in_sizes[0] / HH;
    int grid = B / (WPB * ROWS);   // 131072/256 = 512 blocks -> 2/CU, full residency

    hipLaunchKernelGGL(langnn_mfma16, dim3(grid), dim3(BLK), 0, stream,
                       state, Wih_e, Whh_e, bih_e, bhh_e,
                       Wih_d, Whh_d, bih_d, bhh_d, Wact, bact,
                       (float*)d_out, B);
}